// Round 9
// baseline (310.911 us; speedup 1.0000x reference)
//
#include <hip/hip_runtime.h>

#define B_ 64
#define C_ 128
#define T_ 128
#define J_ 25
#define PIT 136   // k_attn LDS pitch (ushorts)
#define XP 40     // F j-pitch (ushorts)
#define GP 136    // G^T c-pitch (ushorts): 272B rows, 16B aligned
#define TT 2      // t's per k_main block

typedef unsigned short ushort_t;
typedef __attribute__((ext_vector_type(8))) unsigned short ushort8;
typedef __attribute__((ext_vector_type(4))) unsigned short ushort4_t;
typedef __attribute__((ext_vector_type(2))) unsigned short ushort2_t;
typedef __attribute__((ext_vector_type(8))) _Float16 half8;
typedef __attribute__((ext_vector_type(4))) float f32x4;
typedef __attribute__((ext_vector_type(2))) float f32x2;
// relaxed-alignment variants for odd-offset rows
typedef float f32x4u __attribute__((ext_vector_type(4), aligned(4)));
typedef float f32x2u __attribute__((ext_vector_type(2), aligned(4)));
typedef unsigned short ushort8u __attribute__((ext_vector_type(8), aligned(2)));
typedef unsigned short ushort2u __attribute__((ext_vector_type(2), aligned(2)));

__device__ __forceinline__ float bf2f(ushort_t u) {
  unsigned int v = ((unsigned int)u) << 16;
  return __builtin_bit_cast(float, v);
}
__device__ __forceinline__ ushort_t f2bf(float f) {
  unsigned int u = __builtin_bit_cast(unsigned int, f);
  u += 0x7FFFu + ((u >> 16) & 1u);
  return (ushort_t)(u >> 16);
}
__device__ __forceinline__ ushort_t f2h_bits(float f) {
  _Float16 h = (_Float16)f;
  return __builtin_bit_cast(ushort_t, h);
}
__device__ __forceinline__ float h2f(ushort_t u) {
  return (float)__builtin_bit_cast(_Float16, u);
}
__device__ __forceinline__ half8 cvt_bf8_h8(ushort8 u) {
  half8 r;
#pragma unroll
  for (int i = 0; i < 8; ++i) r[i] = (_Float16)bf2f(u[i]);
  return r;
}
__device__ __forceinline__ float ldv(const void* p, long i, int isf32) {
  return isf32 ? ((const float*)p)[i] : bf2f(((const ushort_t*)p)[i]);
}
// vectorized 8-element load (offset i must be a multiple of 8 -> 32B aligned f32)
__device__ __forceinline__ half8 ld8h(const void* p, long i, int isf32) {
  half8 r;
  if (isf32) {
    const float* f = (const float*)p + i;
    f32x4 v0 = *(const f32x4*)f;
    f32x4 v1 = *(const f32x4*)(f + 4);
#pragma unroll
    for (int k = 0; k < 4; ++k) {
      r[k] = (_Float16)v0[k];
      r[4 + k] = (_Float16)v1[k];
    }
  } else {
    ushort8 u = *(const ushort8*)((const ushort_t*)p + i);
    r = cvt_bf8_h8(u);
  }
  return r;
}

// inline dtype detect: sample 64 consecutive words of a tensor this block reads.
__device__ __forceinline__ int detect_isf32(const void* p, int tid) {
  const ushort_t* u = (const ushort_t*)p;
  float a = fabsf(bf2f(u[2 * (tid & 63)]));
  int ok = (a > 1e-4f && a < 64.f) ? 1 : 0;
  unsigned long long m = __ballot(ok);
  return (__popcll(m) > 32) ? 0 : 1;
}

// ------------- kernel 1: x_t[b,j,c] = mean over T (f16 out), LDS-staged -----
__global__ __launch_bounds__(256) void k_mean(const void* __restrict__ x,
                                              ushort_t* __restrict__ xt) {
  const int bc = blockIdx.x;  // b*128 + c
  const int b = bc >> 7, c = bc & 127;
  const long base = (long)bc * 3200;
  const int tid = threadIdx.x;
  const int isf32 = detect_isf32((const ushort_t*)x + base, tid);
  __shared__ float pl[3200];
  __shared__ float red[8][32];
  if (isf32) {
    const f32x4* src = (const f32x4*)((const float*)x + base);
    for (int i = tid; i < 800; i += 256) *(f32x4*)&pl[i * 4] = src[i];
  } else {
    const ushort8* src = (const ushort8*)((const ushort_t*)x + base);
    for (int i = tid; i < 400; i += 256) {
      ushort8 u = src[i];
      f32x4 v0, v1;
#pragma unroll
      for (int r = 0; r < 4; ++r) {
        v0[r] = bf2f(u[r]);
        v1[r] = bf2f(u[4 + r]);
      }
      *(f32x4*)&pl[i * 8] = v0;
      *(f32x4*)&pl[i * 8 + 4] = v1;
    }
  }
  __syncthreads();
  const int j = tid & 31, g = tid >> 5;
  float s = 0.f;
  if (j < J_) {
#pragma unroll
    for (int i = 0; i < 16; ++i) s += pl[(g * 16 + i) * 25 + j];
  }
  red[g][j] = s;
  __syncthreads();
  if (tid < 32) {
    float tot = 0.f;
#pragma unroll
    for (int gg = 0; gg < 8; ++gg) tot += red[gg][tid];
    if (tid < J_) xt[b * 4096 + tid * 128 + c] = f2h_bits(tot * (1.0f / 128.0f));
  }
}

// ---------------- kernel 2: per-batch attention -> F[b] (f16), s[b] ---------
// 512 threads: wave-groups 0-3 compute Wk GEMM, 4-7 compute Wq GEMM in
// parallel; adj staged in LDS for the F phase.
__global__ __launch_bounds__(512) void k_attn(
    const ushort_t* __restrict__ xt, const void* __restrict__ adj,
    const void* __restrict__ Wk, const void* __restrict__ bk,
    const void* __restrict__ Wq, const void* __restrict__ bq,
    const void* __restrict__ alphap, ushort_t* __restrict__ fkws,
    float* __restrict__ sws) {
  const int b = blockIdx.x;
  const int tid = threadIdx.x;
  const int isf32 = detect_isf32(Wk, tid);
  const int wv = tid >> 6, lane = tid & 63, lrow = lane & 15, quad = lane >> 4;
  const int mg = wv >> 2, wvv = wv & 3;
  const float alpha = ldv(alphap, 0, isf32);

  __shared__ __align__(16) ushort_t xtT[32 * PIT];  // f16, [j][c]
  __shared__ __align__(16) ushort_t kkT[32 * PIT];  // f16, [k][o]
  __shared__ __align__(16) ushort_t qqT[32 * PIT];  // f16, [j][o]
  __shared__ float sc[32 * 33];
  __shared__ float adjL[25 * 26];

  // vectorized f16 copy: 32 rows x 17 vec8 (PIT=136=17*8)
  for (int idx = tid; idx < 32 * 17; idx += 512) {
    int r = idx / 17, c8 = idx % 17;
    ushort8 v = {};
    if (r < J_ && c8 < 16) v = *(const ushort8*)&xt[b * 4096 + r * 128 + c8 * 8];
    *(ushort8*)&xtT[r * PIT + c8 * 8] = v;
  }
  // stage adj (25x25) into LDS, pitch 26
  for (int idx = tid; idx < 625; idx += 512)
    adjL[(idx / 25) * 26 + (idx % 25)] = ldv(adj, idx, isf32);
  __syncthreads();

  {  // both W GEMMs in parallel across wave-groups
    const void* W = mg ? Wq : Wk;
    const void* bias = mg ? bq : bk;
    ushort_t* dstT = mg ? qqT : kkT;
    f32x4 acc[2][2] = {};
    for (int ks = 0; ks < 4; ++ks) {
      half8 bfr[2];
#pragma unroll
      for (int jt = 0; jt < 2; ++jt)
        bfr[jt] = *(const half8*)&xtT[(jt * 16 + lrow) * PIT + ks * 32 + quad * 8];
#pragma unroll
      for (int ot = 0; ot < 2; ++ot) {
        int o = (2 * wvv + ot) * 16 + lrow;
        half8 afr = ld8h(W, o * 128 + ks * 32 + quad * 8, isf32);
#pragma unroll
        for (int jt = 0; jt < 2; ++jt)
          acc[ot][jt] = __builtin_amdgcn_mfma_f32_16x16x32_f16(afr, bfr[jt],
                                                               acc[ot][jt], 0, 0, 0);
      }
    }
#pragma unroll
    for (int ot = 0; ot < 2; ++ot) {
      int obase = (2 * wvv + ot) * 16 + quad * 4;
#pragma unroll
      for (int jt = 0; jt < 2; ++jt) {
        int j = jt * 16 + lrow;
        ushort_t pack[4];
#pragma unroll
        for (int r = 0; r < 4; ++r)
          pack[r] = f2h_bits(acc[ot][jt][r] + ldv(bias, obase + r, isf32));
        *(ushort4_t*)&dstT[j * PIT + obase] = *(ushort4_t*)pack;
      }
    }
  }
  __syncthreads();

  if (wv < 4) {
    const int mt = wv >> 1, nt = wv & 1;
    f32x4 acc = {};
    for (int ks = 0; ks < 4; ++ks) {
      half8 afr = *(const half8*)&qqT[(mt * 16 + lrow) * PIT + ks * 32 + quad * 8];
      half8 bfr = *(const half8*)&kkT[(nt * 16 + lrow) * PIT + ks * 32 + quad * 8];
      acc = __builtin_amdgcn_mfma_f32_16x16x32_f16(afr, bfr, acc, 0, 0, 0);
    }
    const float rs = 0.08838834764831845f;  // 1/sqrt(128)
#pragma unroll
    for (int r = 0; r < 4; ++r)
      sc[(mt * 16 + quad * 4 + r) * 33 + nt * 16 + lrow] = acc[r] * rs;
  }
  __syncthreads();

  if (tid < J_) {
    float m = -1e30f;
    for (int k = 0; k < J_; ++k) m = fmaxf(m, sc[tid * 33 + k]);
    float sum = 0.f;
    for (int k = 0; k < J_; ++k) {
      float e = expf(sc[tid * 33 + k] - m);
      sc[tid * 33 + k] = e;
      sum += e;
    }
    float inv = 1.f / sum;
    for (int k = 0; k < J_; ++k) sc[tid * 33 + k] *= inv;
  }
  __syncthreads();

  for (int idx = tid; idx < 1280; idx += 512) {
    int k = idx / XP, jj = idx % XP;
    float v = 0.f;
    if (k < J_ && jj < J_) {
      v = adjL[jj * 26 + k];
      float d = 0.f;
      for (int m = 0; m < J_; ++m) d += adjL[jj * 26 + m] * sc[m * 33 + k];
      v += alpha * d;
    }
    fkws[b * 1280 + idx] = f2h_bits(v);
  }
  if (tid < 32) {
    float v = 0.f;
    if (tid < J_) {
      float d = 0.f;
      for (int jj = 0; jj < J_; ++jj) d += sc[jj * 33 + tid];
      v = 1.f + alpha * d;
    }
    sws[b * 32 + tid] = v;
  }
}

// ------- kernel 3: per (b, 2 t's): out = relu(BN(Ws @ (x@F) + bs*s)) --------
// TT=2 occupancy experiment: LDS ~18KB -> up to 8 blocks/CU, grid 4096.
// Structure identical to R7 (stage-A xa hoist kept, loads never cross a
// barrier -> no spill). XCD swizzle keeps adjacent tb (which share output
// 64B boundary lines) on one XCD so L2 merges the 200B chunks.
#define SM_FK 0
#define SM_GT 2560
#define SM_TOT (2560 + 50 * GP * 2)  // 16160
__global__ __launch_bounds__(256, 6) void k_main(
    const void* __restrict__ x, const void* __restrict__ Ws,
    const void* __restrict__ bs, const void* __restrict__ gamma,
    const void* __restrict__ beta, const void* __restrict__ rmean,
    const void* __restrict__ rvar, const ushort_t* __restrict__ fkws,
    const float* __restrict__ sws, void* __restrict__ out) {
  const int tid = threadIdx.x;
  const int isf32 = detect_isf32(Ws, tid);
  // XCD-bijective swizzle: grid 4096 % 8 == 0; XCD x gets idx0 chunk
  // [512x, 512x+512) = 8 full batches (64 tb each, contiguous).
  const int p = blockIdx.x;
  const int idx0 = (p & 7) * 512 + (p >> 3);
  const int b = idx0 >> 6, tb = idx0 & 63, t0 = tb * TT;
  const int wv = tid >> 6, lane = tid & 63, lrow = lane & 15, quad = lane >> 4;

  __shared__ __align__(16) char smem[SM_TOT];
  __shared__ float bnscale[128], bnshift[128], bsv[128], sv[32];
  ushort_t* fk = (ushort_t*)(smem + SM_FK);      // F^T [k][j] pitch 40
  ushort_t* gt = (ushort_t*)(smem + SM_GT);      // G^T f16 [n][c] pitch 136, 50 rows
  ushort_t* outbuf = (ushort_t*)(smem + SM_GT);  // f16 [o][n] pitch 50 (reuse)

  // tiny staging: fk (vec8), bn params
  for (int i = tid; i < 160; i += 256)
    *(ushort8*)&fk[i * 8] = *(const ushort8*)&fkws[b * 1280 + i * 8];
  if (tid < 32) sv[tid] = sws[b * 32 + tid];
  if (tid < 128) {
    float g = ldv(gamma, tid, isf32), v = ldv(rvar, tid, isf32);
    float scl = g * rsqrtf(v + 1e-5f);
    bnscale[tid] = scl;
    bnshift[tid] = ldv(beta, tid, isf32) - ldv(rmean, tid, isf32) * scl;
    bsv[tid] = ldv(bs, tid, isf32);
  }
  __syncthreads();

  // ---- stage A: G^T[(t,k)][c] = sum_j F^T[k][j]*x[c][j] ----
  // fk cols [25,40) are zero -> K-pad garbage annihilated. quad3 loads only
  // j=24 (scalar) so no OOB. 4 x-loads hoisted (no barrier in live range).
  {
    half8 afr[2];
#pragma unroll
    for (int mt = 0; mt < 2; ++mt)
      afr[mt] = *(const half8*)&fk[(mt * 16 + lrow) * XP + quad * 8];
    const float* xf = (const float*)x;
    const ushort_t* xh = (const ushort_t*)x;

    half8 xa[2 * TT];  // static indexing only (fully unrolled) -> VGPRs
#pragma unroll
    for (int t = 0; t < TT; ++t) {
#pragma unroll
      for (int ci = 0; ci < 2; ++ci) {
        int ct = 2 * wv + ci;
        long pp = (long)b * 409600 + (long)(ct * 16 + lrow) * 3200 + (t0 + t) * 25;
        half8 bfr;
        if (quad < 3) {
          if (isf32) {
            f32x4u v0 = *(const f32x4u*)(xf + pp + quad * 8);
            f32x4u v1 = *(const f32x4u*)(xf + pp + quad * 8 + 4);
#pragma unroll
            for (int r = 0; r < 4; ++r) {
              bfr[r] = (_Float16)v0[r];
              bfr[4 + r] = (_Float16)v1[r];
            }
          } else {
            ushort8u u = *(const ushort8u*)(xh + pp + quad * 8);
#pragma unroll
            for (int r = 0; r < 8; ++r) bfr[r] = (_Float16)bf2f(u[r]);
          }
        } else {
          bfr = (half8){};
          bfr[0] = (_Float16)(isf32 ? xf[pp + 24] : bf2f(xh[pp + 24]));
        }
        xa[t * 2 + ci] = bfr;
      }
    }

#pragma unroll
    for (int t = 0; t < TT; ++t) {
#pragma unroll
      for (int ci = 0; ci < 2; ++ci) {
        int ct = 2 * wv + ci;
        f32x4 accg[2] = {};
#pragma unroll
        for (int mt = 0; mt < 2; ++mt)
          accg[mt] = __builtin_amdgcn_mfma_f32_16x16x32_f16(afr[mt], xa[t * 2 + ci],
                                                            accg[mt], 0, 0, 0);
#pragma unroll
        for (int mt = 0; mt < 2; ++mt)
#pragma unroll
          for (int r = 0; r < 4; ++r) {
            int kk = mt * 16 + quad * 4 + r;
            if (kk < J_)
              gt[(t * 25 + kk) * GP + ct * 16 + lrow] = f2h_bits(accg[mt][r]);
          }
      }
    }
  }

  // Ws A-fragments (issued here so they fly across the barrier)
  half8 wsf[2][4];
#pragma unroll
  for (int ot = 0; ot < 2; ++ot) {
    int o = (2 * wv + ot) * 16 + lrow;
#pragma unroll
    for (int ks = 0; ks < 4; ++ks)
      wsf[ot][ks] = ld8h(Ws, o * 128 + ks * 32 + quad * 8, isf32);
  }
  __syncthreads();

  // ---- stage B: H[o][n] = sum_c Ws[o][c]*G^T[n][c], n in [0,64) ----
  // rows >= 50 don't exist: predicate the nt=3 fragment (rows 48,49 only).
  f32x4 acc[2][4];
#pragma unroll
  for (int ot = 0; ot < 2; ++ot)
#pragma unroll
    for (int nt = 0; nt < 4; ++nt) acc[ot][nt] = (f32x4){};
  for (int ks = 0; ks < 4; ++ks) {
#pragma unroll
    for (int nt = 0; nt < 4; ++nt) {
      half8 bfr = (half8){};
      if (nt < 3 || lrow < 2)
        bfr = *(const half8*)&gt[(nt * 16 + lrow) * GP + ks * 32 + quad * 8];
#pragma unroll
      for (int ot = 0; ot < 2; ++ot)
        acc[ot][nt] = __builtin_amdgcn_mfma_f32_16x16x32_f16(wsf[ot][ks], bfr,
                                                             acc[ot][nt], 0, 0, 0);
    }
  }
  __syncthreads();  // gt reads done; outbuf may overwrite

  // ---- epilogue into LDS f16 [o][n] pitch 50 ----
#pragma unroll
  for (int nt = 0; nt < 4; ++nt) {
    int n = nt * 16 + lrow;
    if (n < 50) {
      float svk = sv[n % 25];
#pragma unroll
      for (int ot = 0; ot < 2; ++ot) {
        int obase = (2 * wv + ot) * 16 + quad * 4;
#pragma unroll
        for (int r = 0; r < 4; ++r) {
          int o = obase + r;
          float v = acc[ot][nt][r] + bsv[o] * svk;
          v = v * bnscale[o] + bnshift[o];
          outbuf[o * 50 + n] = f2h_bits(fmaxf(v, 0.f));
        }
      }
    }
  }
  __syncthreads();

  // ---- vectorized store: per o, 50 contiguous elements (2 per thread-iter) --
  {
    const long obase = ((long)(b * 128) * 128 + t0) * 25;
    if (isf32) {
      float* of = (float*)out + obase;
      for (int i2 = tid; i2 < 3200; i2 += 256) {
        int o = i2 / 25, q = i2 % 25;
        ushort2u u = *(const ushort2u*)&outbuf[o * 50 + q * 2];
        f32x2u v = {h2f(u[0]), h2f(u[1])};
        *(f32x2u*)(of + (long)o * 3200 + q * 2) = v;
      }
    } else {
      ushort_t* oh = (ushort_t*)out + obase;
      for (int i2 = tid; i2 < 3200; i2 += 256) {
        int o = i2 / 25, q = i2 % 25;
        ushort2u u = *(const ushort2u*)&outbuf[o * 50 + q * 2];
        ushort2u w = {f2bf(h2f(u[0])), f2bf(h2f(u[1]))};
        *(ushort2u*)(oh + (long)o * 3200 + q * 2) = w;
      }
    }
  }
}

extern "C" void kernel_launch(void* const* d_in, const int* in_sizes, int n_in,
                              void* d_out, int out_size, void* d_ws, size_t ws_size,
                              hipStream_t stream) {
  const void* x = d_in[0];
  const void* adj = d_in[1];
  const void* Wk = d_in[2];
  const void* bk = d_in[3];
  const void* Wq = d_in[4];
  const void* bq = d_in[5];
  const void* Ws = d_in[6];
  const void* bsp = d_in[7];
  const void* gamma = d_in[8];
  const void* beta = d_in[9];
  const void* rmean = d_in[10];
  const void* rvar = d_in[11];
  const void* alphap = d_in[12];

  char* ws = (char*)d_ws;
  ushort_t* xt = (ushort_t*)ws;                            // 64*4096 f16 = 512 KiB
  ushort_t* fkws = (ushort_t*)(ws + 64 * 4096 * 2);        // 64*1280 f16
  float* sws = (float*)(ws + 64 * 4096 * 2 + 64 * 1280 * 2);

  k_mean<<<B_ * C_, 256, 0, stream>>>(x, xt);
  k_attn<<<B_, 512, 0, stream>>>(xt, adj, Wk, bk, Wq, bq, alphap, fkws, sws);
  k_main<<<B_ * (T_ / TT), 256, 0, stream>>>(x, Ws, bsp, gamma, beta, rmean, rvar,
                                             fkws, sws, d_out);
}

// Round 10
// 269.125 us; speedup vs baseline: 1.1553x; 1.1553x over previous
//
#include <hip/hip_runtime.h>

#define B_ 64
#define C_ 128
#define T_ 128
#define J_ 25
#define PIT 136   // k_attn LDS pitch (ushorts)
#define XP 40     // F j-pitch (ushorts)
#define GP 136    // G^T c-pitch (ushorts): 272B rows, 16B aligned
#define TT 4      // t's per k_main block

typedef unsigned short ushort_t;
typedef __attribute__((ext_vector_type(8))) unsigned short ushort8;
typedef __attribute__((ext_vector_type(4))) unsigned short ushort4_t;
typedef __attribute__((ext_vector_type(8))) _Float16 half8;
typedef __attribute__((ext_vector_type(4))) float f32x4;
// relaxed-alignment variants for odd-offset rows
typedef float f32x4u __attribute__((ext_vector_type(4), aligned(4)));
typedef unsigned short ushort8u __attribute__((ext_vector_type(8), aligned(2)));

__device__ __forceinline__ float bf2f(ushort_t u) {
  unsigned int v = ((unsigned int)u) << 16;
  return __builtin_bit_cast(float, v);
}
__device__ __forceinline__ ushort_t f2bf(float f) {
  unsigned int u = __builtin_bit_cast(unsigned int, f);
  u += 0x7FFFu + ((u >> 16) & 1u);
  return (ushort_t)(u >> 16);
}
__device__ __forceinline__ ushort_t f2h_bits(float f) {
  _Float16 h = (_Float16)f;
  return __builtin_bit_cast(ushort_t, h);
}
__device__ __forceinline__ float h2f(ushort_t u) {
  return (float)__builtin_bit_cast(_Float16, u);
}
__device__ __forceinline__ half8 cvt_bf8_h8(ushort8 u) {
  half8 r;
#pragma unroll
  for (int i = 0; i < 8; ++i) r[i] = (_Float16)bf2f(u[i]);
  return r;
}
__device__ __forceinline__ float ldv(const void* p, long i, int isf32) {
  return isf32 ? ((const float*)p)[i] : bf2f(((const ushort_t*)p)[i]);
}
// vectorized 8-element load (offset i must be a multiple of 8 -> 32B aligned f32)
__device__ __forceinline__ half8 ld8h(const void* p, long i, int isf32) {
  half8 r;
  if (isf32) {
    const float* f = (const float*)p + i;
    f32x4 v0 = *(const f32x4*)f;
    f32x4 v1 = *(const f32x4*)(f + 4);
#pragma unroll
    for (int k = 0; k < 4; ++k) {
      r[k] = (_Float16)v0[k];
      r[4 + k] = (_Float16)v1[k];
    }
  } else {
    ushort8 u = *(const ushort8*)((const ushort_t*)p + i);
    r = cvt_bf8_h8(u);
  }
  return r;
}

// inline dtype detect: sample 64 consecutive words of a tensor this block reads.
__device__ __forceinline__ int detect_isf32(const void* p, int tid) {
  const ushort_t* u = (const ushort_t*)p;
  float a = fabsf(bf2f(u[2 * (tid & 63)]));
  int ok = (a > 1e-4f && a < 64.f) ? 1 : 0;
  unsigned long long m = __ballot(ok);
  return (__popcll(m) > 32) ? 0 : 1;
}

// -- kernel 1: x_t[b,j,c] = mean over T (f16 out). 4 adjacent c-planes/block
// -- (contiguous 51.2KB global stretch), reduction amortized across planes.
__global__ __launch_bounds__(256) void k_mean(const void* __restrict__ x,
                                              ushort_t* __restrict__ xt) {
  const int bg = blockIdx.x;             // b*32 + cg
  const int b = bg >> 5, cg = bg & 31;   // cg -> c0 = cg*4
  const int c0 = cg * 4;
  const long base = (long)(b * 128 + c0) * 3200;
  const int tid = threadIdx.x;
  const int isf32 = detect_isf32((const ushort_t*)x + base, tid);
  __shared__ float pl[3200];
  __shared__ float redAll[4][8][32];

  for (int p = 0; p < 4; ++p) {
    const long pbase = base + (long)p * 3200;
    if (isf32) {
      const f32x4* src = (const f32x4*)((const float*)x + pbase);
      for (int i = tid; i < 800; i += 256) *(f32x4*)&pl[i * 4] = src[i];
    } else {
      const ushort8* src = (const ushort8*)((const ushort_t*)x + pbase);
      for (int i = tid; i < 400; i += 256) {
        ushort8 u = src[i];
        f32x4 v0, v1;
#pragma unroll
        for (int r = 0; r < 4; ++r) {
          v0[r] = bf2f(u[r]);
          v1[r] = bf2f(u[4 + r]);
        }
        *(f32x4*)&pl[i * 8] = v0;
        *(f32x4*)&pl[i * 8 + 4] = v1;
      }
    }
    __syncthreads();
    const int j = tid & 31, g = tid >> 5;
    float s = 0.f;
    if (j < J_) {
#pragma unroll
      for (int i = 0; i < 16; ++i) s += pl[(g * 16 + i) * 25 + j];
    }
    redAll[p][g][j] = s;
    __syncthreads();  // reduce reads done; next plane may overwrite pl
  }

  if (tid < 128) {
    const int p = tid >> 5, j = tid & 31;
    if (j < J_) {
      float tot = 0.f;
#pragma unroll
      for (int gg = 0; gg < 8; ++gg) tot += redAll[p][gg][j];
      xt[b * 4096 + j * 128 + c0 + p] = f2h_bits(tot * (1.0f / 128.0f));
    }
  }
}

// ---------------- kernel 2: per-batch attention -> F[b] (f16), s[b] ---------
// 512 threads: wave-groups 0-3 compute Wk GEMM, 4-7 compute Wq GEMM in
// parallel; adj staged in LDS for the F phase. (unchanged from R7)
__global__ __launch_bounds__(512) void k_attn(
    const ushort_t* __restrict__ xt, const void* __restrict__ adj,
    const void* __restrict__ Wk, const void* __restrict__ bk,
    const void* __restrict__ Wq, const void* __restrict__ bq,
    const void* __restrict__ alphap, ushort_t* __restrict__ fkws,
    float* __restrict__ sws) {
  const int b = blockIdx.x;
  const int tid = threadIdx.x;
  const int isf32 = detect_isf32(Wk, tid);
  const int wv = tid >> 6, lane = tid & 63, lrow = lane & 15, quad = lane >> 4;
  const int mg = wv >> 2, wvv = wv & 3;
  const float alpha = ldv(alphap, 0, isf32);

  __shared__ __align__(16) ushort_t xtT[32 * PIT];  // f16, [j][c]
  __shared__ __align__(16) ushort_t kkT[32 * PIT];  // f16, [k][o]
  __shared__ __align__(16) ushort_t qqT[32 * PIT];  // f16, [j][o]
  __shared__ float sc[32 * 33];
  __shared__ float adjL[25 * 26];

  // vectorized f16 copy: 32 rows x 17 vec8 (PIT=136=17*8)
  for (int idx = tid; idx < 32 * 17; idx += 512) {
    int r = idx / 17, c8 = idx % 17;
    ushort8 v = {};
    if (r < J_ && c8 < 16) v = *(const ushort8*)&xt[b * 4096 + r * 128 + c8 * 8];
    *(ushort8*)&xtT[r * PIT + c8 * 8] = v;
  }
  // stage adj (25x25) into LDS, pitch 26
  for (int idx = tid; idx < 625; idx += 512)
    adjL[(idx / 25) * 26 + (idx % 25)] = ldv(adj, idx, isf32);
  __syncthreads();

  {  // both W GEMMs in parallel across wave-groups
    const void* W = mg ? Wq : Wk;
    const void* bias = mg ? bq : bk;
    ushort_t* dstT = mg ? qqT : kkT;
    f32x4 acc[2][2] = {};
    for (int ks = 0; ks < 4; ++ks) {
      half8 bfr[2];
#pragma unroll
      for (int jt = 0; jt < 2; ++jt)
        bfr[jt] = *(const half8*)&xtT[(jt * 16 + lrow) * PIT + ks * 32 + quad * 8];
#pragma unroll
      for (int ot = 0; ot < 2; ++ot) {
        int o = (2 * wvv + ot) * 16 + lrow;
        half8 afr = ld8h(W, o * 128 + ks * 32 + quad * 8, isf32);
#pragma unroll
        for (int jt = 0; jt < 2; ++jt)
          acc[ot][jt] = __builtin_amdgcn_mfma_f32_16x16x32_f16(afr, bfr[jt],
                                                               acc[ot][jt], 0, 0, 0);
      }
    }
#pragma unroll
    for (int ot = 0; ot < 2; ++ot) {
      int obase = (2 * wvv + ot) * 16 + quad * 4;
#pragma unroll
      for (int jt = 0; jt < 2; ++jt) {
        int j = jt * 16 + lrow;
        ushort_t pack[4];
#pragma unroll
        for (int r = 0; r < 4; ++r)
          pack[r] = f2h_bits(acc[ot][jt][r] + ldv(bias, obase + r, isf32));
        *(ushort4_t*)&dstT[j * PIT + obase] = *(ushort4_t*)pack;
      }
    }
  }
  __syncthreads();

  if (wv < 4) {
    const int mt = wv >> 1, nt = wv & 1;
    f32x4 acc = {};
    for (int ks = 0; ks < 4; ++ks) {
      half8 afr = *(const half8*)&qqT[(mt * 16 + lrow) * PIT + ks * 32 + quad * 8];
      half8 bfr = *(const half8*)&kkT[(nt * 16 + lrow) * PIT + ks * 32 + quad * 8];
      acc = __builtin_amdgcn_mfma_f32_16x16x32_f16(afr, bfr, acc, 0, 0, 0);
    }
    const float rs = 0.08838834764831845f;  // 1/sqrt(128)
#pragma unroll
    for (int r = 0; r < 4; ++r)
      sc[(mt * 16 + quad * 4 + r) * 33 + nt * 16 + lrow] = acc[r] * rs;
  }
  __syncthreads();

  if (tid < J_) {
    float m = -1e30f;
    for (int k = 0; k < J_; ++k) m = fmaxf(m, sc[tid * 33 + k]);
    float sum = 0.f;
    for (int k = 0; k < J_; ++k) {
      float e = expf(sc[tid * 33 + k] - m);
      sc[tid * 33 + k] = e;
      sum += e;
    }
    float inv = 1.f / sum;
    for (int k = 0; k < J_; ++k) sc[tid * 33 + k] *= inv;
  }
  __syncthreads();

  for (int idx = tid; idx < 1280; idx += 512) {
    int k = idx / XP, jj = idx % XP;
    float v = 0.f;
    if (k < J_ && jj < J_) {
      v = adjL[jj * 26 + k];
      float d = 0.f;
      for (int m = 0; m < J_; ++m) d += adjL[jj * 26 + m] * sc[m * 33 + k];
      v += alpha * d;
    }
    fkws[b * 1280 + idx] = f2h_bits(v);
  }
  if (tid < 32) {
    float v = 0.f;
    if (tid < J_) {
      float d = 0.f;
      for (int jj = 0; jj < J_; ++jj) d += sc[jj * 33 + tid];
      v = 1.f + alpha * d;
    }
    sws[b * 32 + tid] = v;
  }
}

// ------- kernel 3: per (b, 4 t's): out = relu(BN(Ws @ (x@F) + bs*s)) --------
// R7 structure, minus the fk LDS stage + its barrier: each lane reads its F^T
// fragment straight from fkws (f16 bits, 16B-aligned, L2-hot, zero-padded
// cols [25,40)). 3 barriers total. xa hoist kept (no barrier in live range).
#define SM_TOT (100 * GP * 2)  // 27200: gt only; outbuf reuses gt
__global__ __launch_bounds__(256, 4) void k_main(
    const void* __restrict__ x, const void* __restrict__ Ws,
    const void* __restrict__ bs, const void* __restrict__ gamma,
    const void* __restrict__ beta, const void* __restrict__ rmean,
    const void* __restrict__ rvar, const ushort_t* __restrict__ fkws,
    const float* __restrict__ sws, void* __restrict__ out) {
  const int tid = threadIdx.x;
  const int isf32 = detect_isf32(Ws, tid);
  // XCD-bijective swizzle: grid 2048 % 8 == 0; each XCD gets a contiguous
  // 256-block chunk (8 batches x 32 t-blocks).
  const int p = blockIdx.x;
  const int idx0 = (p & 7) * 256 + (p >> 3);
  const int b = idx0 >> 5, tb = idx0 & 31, t0 = tb * TT;
  const int wv = tid >> 6, lane = tid & 63, lrow = lane & 15, quad = lane >> 4;

  __shared__ __align__(16) char smem[SM_TOT];
  __shared__ float bnscale[128], bnshift[128], bsv[128], sv[32];
  ushort_t* gt = (ushort_t*)smem;      // G^T f16 [n][c] pitch 136, 100 rows
  ushort_t* outbuf = (ushort_t*)smem;  // f16 [o][n] pitch 100 (reuse)

  // bn/sv staging: writes ordered before epilogue reads by barriers 1+2.
  if (tid < 32) sv[tid] = sws[b * 32 + tid];
  if (tid < 128) {
    float g = ldv(gamma, tid, isf32), v = ldv(rvar, tid, isf32);
    float scl = g * rsqrtf(v + 1e-5f);
    bnscale[tid] = scl;
    bnshift[tid] = ldv(beta, tid, isf32) - ldv(rmean, tid, isf32) * scl;
    bsv[tid] = ldv(bs, tid, isf32);
  }

  // ---- stage A: G^T[(t,k)][c] = sum_j F^T[k][j]*x[c][j] ----
  // afr direct from fkws (zero cols [25,40) annihilate K-pad garbage).
  // quad3 loads only j=24 (scalar) so no OOB. 8 x-loads hoisted.
  {
    half8 afr[2];
#pragma unroll
    for (int mt = 0; mt < 2; ++mt)
      afr[mt] = *(const half8*)&fkws[b * 1280 + (mt * 16 + lrow) * XP + quad * 8];
    const float* xf = (const float*)x;
    const ushort_t* xh = (const ushort_t*)x;

    half8 xa[8];  // static indexing only (fully unrolled) -> stays in VGPRs
#pragma unroll
    for (int t = 0; t < TT; ++t) {
#pragma unroll
      for (int ci = 0; ci < 2; ++ci) {
        int ct = 2 * wv + ci;
        long pp = (long)b * 409600 + (long)(ct * 16 + lrow) * 3200 + (t0 + t) * 25;
        half8 bfr;
        if (quad < 3) {
          if (isf32) {
            f32x4u v0 = *(const f32x4u*)(xf + pp + quad * 8);
            f32x4u v1 = *(const f32x4u*)(xf + pp + quad * 8 + 4);
#pragma unroll
            for (int r = 0; r < 4; ++r) {
              bfr[r] = (_Float16)v0[r];
              bfr[4 + r] = (_Float16)v1[r];
            }
          } else {
            ushort8u u = *(const ushort8u*)(xh + pp + quad * 8);
#pragma unroll
            for (int r = 0; r < 8; ++r) bfr[r] = (_Float16)bf2f(u[r]);
          }
        } else {
          bfr = (half8){};
          bfr[0] = (_Float16)(isf32 ? xf[pp + 24] : bf2f(xh[pp + 24]));
        }
        xa[t * 2 + ci] = bfr;
      }
    }

#pragma unroll
    for (int t = 0; t < TT; ++t) {
#pragma unroll
      for (int ci = 0; ci < 2; ++ci) {
        int ct = 2 * wv + ci;
        f32x4 accg[2] = {};
#pragma unroll
        for (int mt = 0; mt < 2; ++mt)
          accg[mt] = __builtin_amdgcn_mfma_f32_16x16x32_f16(afr[mt], xa[t * 2 + ci],
                                                            accg[mt], 0, 0, 0);
#pragma unroll
        for (int mt = 0; mt < 2; ++mt)
#pragma unroll
          for (int r = 0; r < 4; ++r) {
            int kk = mt * 16 + quad * 4 + r;
            if (kk < J_)
              gt[(t * 25 + kk) * GP + ct * 16 + lrow] = f2h_bits(accg[mt][r]);
          }
      }
    }
  }

  // Ws A-fragments (issued here so they fly across the barrier)
  half8 wsf[2][4];
#pragma unroll
  for (int ot = 0; ot < 2; ++ot) {
    int o = (2 * wv + ot) * 16 + lrow;
#pragma unroll
    for (int ks = 0; ks < 4; ++ks)
      wsf[ot][ks] = ld8h(Ws, o * 128 + ks * 32 + quad * 8, isf32);
  }
  __syncthreads();  // barrier 1: gt ready, bn/sv visible

  // ---- stage B: H[o][n] = sum_c Ws[o][c]*G^T[n][c], n in [0,112) ----
  // rows >= 100 don't exist: predicate the nt=6 fragment to zero.
  f32x4 acc[2][7];
#pragma unroll
  for (int ot = 0; ot < 2; ++ot)
#pragma unroll
    for (int nt = 0; nt < 7; ++nt) acc[ot][nt] = (f32x4){};
  for (int ks = 0; ks < 4; ++ks) {
#pragma unroll
    for (int nt = 0; nt < 7; ++nt) {
      half8 bfr = (half8){};
      if (nt < 6 || lrow < 4)
        bfr = *(const half8*)&gt[(nt * 16 + lrow) * GP + ks * 32 + quad * 8];
#pragma unroll
      for (int ot = 0; ot < 2; ++ot)
        acc[ot][nt] = __builtin_amdgcn_mfma_f32_16x16x32_f16(wsf[ot][ks], bfr,
                                                             acc[ot][nt], 0, 0, 0);
    }
  }
  __syncthreads();  // barrier 2: gt reads done; outbuf may overwrite

  // ---- epilogue into LDS f16 [o][n] pitch 100 ----
#pragma unroll
  for (int nt = 0; nt < 7; ++nt) {
    int n = nt * 16 + lrow;
    if (n < 100) {
      float svk = sv[n % 25];
#pragma unroll
      for (int ot = 0; ot < 2; ++ot) {
        int obase = (2 * wv + ot) * 16 + quad * 4;
#pragma unroll
        for (int r = 0; r < 4; ++r) {
          int o = obase + r;
          float v = acc[ot][nt][r] + bsv[o] * svk;
          v = v * bnscale[o] + bnshift[o];
          outbuf[o * 100 + n] = f2h_bits(fmaxf(v, 0.f));
        }
      }
    }
  }
  __syncthreads();  // barrier 3

  // ---- vectorized store: per o, 100 contiguous elements ----
  {
    const long obase = ((long)(b * 128) * 128 + t0) * 25;
    if (isf32) {
      float* of = (float*)out + obase;
      for (int i2 = tid; i2 < 3200; i2 += 256) {
        int o = i2 / 25, q = i2 % 25;
        ushort4_t u = *(const ushort4_t*)&outbuf[o * 100 + q * 4];
        f32x4 v;
#pragma unroll
        for (int r = 0; r < 4; ++r) v[r] = h2f(u[r]);
        *(f32x4*)(of + (long)o * 3200 + q * 4) = v;
      }
    } else {
      ushort_t* oh = (ushort_t*)out + obase;
      for (int i2 = tid; i2 < 3200; i2 += 256) {
        int o = i2 / 25, q = i2 % 25;
        ushort4_t u = *(const ushort4_t*)&outbuf[o * 100 + q * 4];
        ushort4_t w;
#pragma unroll
        for (int r = 0; r < 4; ++r) w[r] = f2bf(h2f(u[r]));
        *(ushort4_t*)(oh + (long)o * 3200 + q * 4) = w;
      }
    }
  }
}

extern "C" void kernel_launch(void* const* d_in, const int* in_sizes, int n_in,
                              void* d_out, int out_size, void* d_ws, size_t ws_size,
                              hipStream_t stream) {
  const void* x = d_in[0];
  const void* adj = d_in[1];
  const void* Wk = d_in[2];
  const void* bk = d_in[3];
  const void* Wq = d_in[4];
  const void* bq = d_in[5];
  const void* Ws = d_in[6];
  const void* bsp = d_in[7];
  const void* gamma = d_in[8];
  const void* beta = d_in[9];
  const void* rmean = d_in[10];
  const void* rvar = d_in[11];
  const void* alphap = d_in[12];

  char* ws = (char*)d_ws;
  ushort_t* xt = (ushort_t*)ws;                            // 64*4096 f16 = 512 KiB
  ushort_t* fkws = (ushort_t*)(ws + 64 * 4096 * 2);        // 64*1280 f16
  float* sws = (float*)(ws + 64 * 4096 * 2 + 64 * 1280 * 2);

  k_mean<<<B_ * 32, 256, 0, stream>>>(x, xt);
  k_attn<<<B_, 512, 0, stream>>>(xt, adj, Wk, bk, Wq, bq, alphap, fkws, sws);
  k_main<<<B_ * (T_ / TT), 256, 0, stream>>>(x, Ws, bsp, gamma, beta, rmean, rvar,
                                             fkws, sws, d_out);
}